// Round 8
// baseline (89.194 us; speedup 1.0000x reference)
//
#include <hip/hip_runtime.h>
#include <math.h>

#define NB 4
#define NPRED 8400
#define NGT 32
#define NCLS 80
#define ROW 85
#define NSEG 132    // ceil(8400/64); last segment has 16 preds

typedef unsigned long long u64;

// ---------- math helpers (mirror reference fp32 op order) ----------

__device__ __forceinline__ float focal_t(float x, float t) {
    float p = 1.f / (1.f + expf(-x));
    float ce = (fmaxf(x, 0.f) + log1pf(expf(-fabsf(x)))) - x * t; // logaddexp(0,x) - x*t
    float pt = p * t + (1.f - p) * (1.f - t);
    float ompt = 1.f - pt;
    float loss = ce * (ompt * ompt);              // GAMMA=2
    float at = 0.25f * t + 0.75f * (1.f - t);     // ALPHA=0.25
    return at * loss;
}

__device__ __forceinline__ float ciou_f(float x1, float y1, float x2, float y2,
                                        float x1g, float y1g, float x2g, float y2g,
                                        float atan_p, float atan_g) {
    float w1 = x2 - x1, h1 = y2 - y1;
    float wg = x2g - x1g, hg = y2g - y1g;
    float iw = fmaxf(fminf(x2, x2g) - fmaxf(x1, x1g), 0.f);
    float ih = fmaxf(fminf(y2, y2g) - fmaxf(y1, y1g), 0.f);
    float inter = iw * ih;
    float uni = w1 * h1 + wg * hg - inter;
    float iou = inter / (uni + 1e-7f);
    float cw = fmaxf(x2, x2g) - fminf(x1, x1g);
    float ch = fmaxf(y2, y2g) - fminf(y1, y1g);
    float diag = cw * cw + ch * ch + 1e-7f;
    float dx = (x1 + x2 - x1g - x2g) * 0.5f;
    float dy = (y1 + y2 - y1g - y2g) * 0.5f;
    float rho2 = dx * dx + dy * dy;
    float diou = 1.f - iou + rho2 / diag;
    float dd = atan_g - atan_p;
    const float CV = (float)(4.0 / (M_PI * M_PI));
    float v = CV * (dd * dd);
    float alpha = v / (1.f - iou + v + 1e-7f);
    return diou + alpha * v;
}

__device__ __forceinline__ u64 wave_min_u64(u64 k) {
    #pragma unroll
    for (int off = 32; off >= 1; off >>= 1) {
        u64 o = __shfl_xor(k, off);
        k = (o < k) ? o : k;
    }
    return k;
}

// key packs (cost_bits, col). cost >= 0 always (ciou >= 0; S0 - f0 >= 0 by
// monotonicity of nonneg float sums; f1 >= 0) -> bit order == value order,
// low word gives the first-index tie-break.
__device__ __forceinline__ u64 pack_key(float v, int idx) {
    return ((u64)__float_as_uint(v) << 32) | (u64)(unsigned)idx;
}

// ---------- K1: fused GT-preproc + staging + S0 + cost + segment minima ----
// Block = (segment sg, batch b). outputs read ONCE, coalesced float4.
// sg==0 blocks persist gtab/larr for K2. buckets direct-write (no atomics).

__global__ __launch_bounds__(256) void fused_kernel(
        const float* __restrict__ outputs, const float* __restrict__ targets,
        float* __restrict__ s0arr, u64* __restrict__ kt,
        double* __restrict__ buckets, float* __restrict__ gtab,
        int* __restrict__ larr) {
    int sg = blockIdx.x, b = blockIdx.y;
    int tid = threadIdx.x;
    int w = tid >> 6, lane = tid & 63;
    int p0 = sg * 64;
    int nv = (sg == NSEG - 1) ? (NPRED - (NSEG - 1) * 64) : 64;   // 16 or 64

    __shared__ float rows[64 * ROW];        // stride 85 floats -> conflict-free
    __shared__ float s_part[4 * 64];
    __shared__ float s_s0[64];
    __shared__ float s_gt[NGT * 5];
    __shared__ int   s_lab[NGT];

    // stage pred rows coalesced (contiguous, 16B-aligned)
    const float4* src4 = (const float4*)(outputs + ((size_t)b * NPRED + p0) * ROW);
    float4* dst4 = (float4*)rows;
    int cnt4 = nv * ROW / 4;                // 1360 or 340, exact
    for (int k = tid; k < cnt4; k += 256) dst4[k] = src4[k];

    // GT boxes (parallel) — same math as reference xywh_to_xyxy + atan
    if (tid < 32) {
        const float* gt = targets + (size_t)(b * NGT + tid) * ROW;
        float xc = gt[0], yc = gt[1], ww = gt[2], hh = gt[3];
        float x1 = xc - ww * 0.5f, y1 = yc - hh * 0.5f;
        float x2 = xc + ww * 0.5f, y2 = yc + hh * 0.5f;
        float at = atanf((x2 - x1) / (y2 - y1));
        s_gt[tid * 5 + 0] = x1; s_gt[tid * 5 + 1] = y1;
        s_gt[tid * 5 + 2] = x2; s_gt[tid * 5 + 3] = y2;
        s_gt[tid * 5 + 4] = at;
        if (sg == 0) {
            float* gp = gtab + (size_t)(b * NGT + tid) * 5;
            gp[0] = x1; gp[1] = y1; gp[2] = x2; gp[3] = y2; gp[4] = at;
        }
    }
    // labels via ballot over the one-hot row (wave w -> 8 GT rows)
    #pragma unroll
    for (int q = 0; q < 8; ++q) {
        int m = w * 8 + q;
        const float* gt = targets + (size_t)(b * NGT + m) * ROW;
        u64 m1 = __ballot(gt[5 + lane] > 0.5f);
        float v2 = (lane < 16) ? gt[69 + lane] : 0.f;
        u64 m2 = __ballot(v2 > 0.5f);
        if (lane == 0) {
            int L = m1 ? (__ffsll(m1) - 1) : (64 + __ffsll(m2) - 1);
            s_lab[m] = L;
            if (sg == 0) larr[b * NGT + m] = L;
        }
    }
    __syncthreads();

    // S0: pred = lane, chunk w covers 20 classes
    {
        float s = 0.f;
        if (lane < nv) {
            const float* r = rows + lane * ROW;
            int c0 = w * 20;
            #pragma unroll
            for (int c = 0; c < 20; ++c) s += focal_t(r[5 + c0 + c], 0.f);
        }
        s_part[w * 64 + lane] = s;
    }
    __syncthreads();
    if (tid < 64) {
        float s = s_part[tid] + s_part[64 + tid] + s_part[128 + tid] + s_part[192 + tid];
        s_s0[tid] = s;
        if (tid < nv) s0arr[b * NPRED + p0 + tid] = s;
        double ng = (tid < nv) ? (double)focal_t(rows[tid * ROW + 4], 0.f) : 0.0;
        #pragma unroll
        for (int off = 32; off >= 1; off >>= 1) ng += __shfl_xor(ng, off);
        if (tid == 0) buckets[b * NSEG + sg] = ng;   // direct write, no atomic
    }
    __syncthreads();

    // cost + packed segment minima: wave w -> GT rows w*8..w*8+7, lane = pred
    bool valid = lane < nv;
    const float* r = rows + lane * ROW;
    float x1 = 0.f, y1 = 0.f, x2 = 0.f, y2 = 0.f, atan_p = 0.f, S0 = 0.f;
    if (valid) {
        float xc = r[0], yc = r[1], ww = r[2], hh = r[3];
        x1 = xc - ww * 0.5f; y1 = yc - hh * 0.5f;
        x2 = xc + ww * 0.5f; y2 = yc + hh * 0.5f;
        atan_p = atanf((x2 - x1) / (y2 - y1));
        S0 = s_s0[lane];
    }
    #pragma unroll
    for (int q = 0; q < 8; ++q) {
        int m = w * 8 + q;
        const float* gp = s_gt + m * 5;
        float cost = INFINITY;
        if (valid) {
            float cc = ciou_f(x1, y1, x2, y2, gp[0], gp[1], gp[2], gp[3],
                              atan_p, gp[4]);
            float xl = r[5 + s_lab[m]];
            cost = cc + (S0 - focal_t(xl, 0.f) + focal_t(xl, 1.f)) / 80.f;
        }
        u64 key = pack_key(cost, valid ? (p0 + lane) : NPRED);
        key = wave_min_u64(key);
        if (lane == 0) kt[(size_t)(b * NGT + m) * NSEG + sg] = key;
    }
}

// ---------- K2: ONE block, wave w = batch w: assignment + finalize ----------
// Assignment = reference "hungarian"'s effective semantics (round-0 note):
// per GT row in order, (value, lowest-col) argmin over non-poisoned columns;
// on collision poison contested col, walk cols ascending poisoning assigned
// ones, take first free (always in word 0: <=32 taken bits). Lazy repair
// recomputes costs; per-row key buffer is wave-local LDS. No cross-block or
// cross-wave state -> deterministic, no atomics, no ws-carried state.

__global__ __launch_bounds__(256) void assign_finalize_kernel(
        const float* __restrict__ outputs, const float* __restrict__ targets,
        const float* __restrict__ s0arr, const u64* __restrict__ kt,
        const double* __restrict__ buckets, const float* __restrict__ gtab,
        const int* __restrict__ larr, float* __restrict__ out) {
    int tid = threadIdx.x;
    int w = tid >> 6, lane = tid & 63;
    int b = w;                               // wave = batch

    __shared__ u64   cur[NB][NSEG];
    __shared__ u64   taken[NB][NSEG], poison[NB][NSEG];
    __shared__ float s_gt[NB][NGT * 5];
    __shared__ int   s_lab[NB][NGT];
    __shared__ int   rmi[NB][NGT];
    __shared__ int   s_midx[NB][NGT];
    __shared__ float s_siou[NB][NGT], s_cls[NB][NGT], s_adj[NB][NGT];
    __shared__ double s_ns[NB];

    // wave-local init + GT tables
    for (int s = lane; s < NSEG; s += 64) { taken[b][s] = 0ull; poison[b][s] = 0ull; }
    for (int k = lane; k < NGT * 5; k += 64) s_gt[b][k] = gtab[b * NGT * 5 + k];
    if (lane < NGT) s_lab[b][lane] = larr[b * NGT + lane];

    // rowmin prologue from global kt: 2 lanes per row, 66 segs each
    {
        int r = lane >> 1, h = lane & 1;
        const u64* kr = kt + ((size_t)b * NGT + r) * NSEG;
        u64 k = ~0ull;
        int sA = h * 66;
        #pragma unroll 4
        for (int s = sA; s < sA + 66; ++s) { u64 v = kr[s]; if (v < k) k = v; }
        u64 o = __shfl_xor(k, 1);
        if (o < k) k = o;
        if (h == 0) rmi[b][r] = (int)(unsigned)(k & 0xffffffffull);
    }

    const float* Ob = outputs + (size_t)b * NPRED * ROW;
    const float* S0b = s0arr + (size_t)b * NPRED;

    for (int i = 0; i < NGT; ++i) {
        int j1 = rmi[b][i];
        if ((poison[b][j1 >> 6] >> (j1 & 63)) & 1ull) {
            // lazy repair: copy row i's keys, recompute poisoned-argmin segments
            const u64* kr = kt + ((size_t)b * NGT + i) * NSEG;
            for (int s = lane; s < NSEG; s += 64) cur[b][s] = kr[s];
            const float* gp = &s_gt[b][i * 5];
            int lab = s_lab[b][i];
            for (int k0 = 0; k0 < NSEG; k0 += 64) {
                int s = k0 + lane;
                int idx0 = (s < NSEG) ? (int)(unsigned)(cur[b][s] & 0xffffffffull) : 0;
                bool inval = (s < NSEG) && (((poison[b][idx0 >> 6] >> (idx0 & 63)) & 1ull) != 0);
                u64 im = __ballot(inval);
                while (im) {
                    int sgg = k0 + (__ffsll(im) - 1);
                    im &= im - 1;
                    int col = (sgg << 6) + lane;
                    bool cv = (col < NPRED) && !((poison[b][col >> 6] >> (col & 63)) & 1ull);
                    float vv = INFINITY;
                    if (cv) {
                        const float* pr = Ob + (size_t)col * ROW;
                        float xc = pr[0], yc = pr[1], ww = pr[2], hh = pr[3];
                        float x1 = xc - ww * 0.5f, y1 = yc - hh * 0.5f;
                        float x2 = xc + ww * 0.5f, y2 = yc + hh * 0.5f;
                        float atan_p = atanf((x2 - x1) / (y2 - y1));
                        float cc = ciou_f(x1, y1, x2, y2, gp[0], gp[1], gp[2], gp[3],
                                          atan_p, gp[4]);
                        float xl = pr[5 + lab];
                        vv = cc + (S0b[col] - focal_t(xl, 0.f) + focal_t(xl, 1.f)) / 80.f;
                    }
                    u64 key = pack_key(vv, cv ? col : NPRED);
                    key = wave_min_u64(key);
                    if (lane == 0) cur[b][sgg] = key;
                }
            }
            // rescan merged row
            u64 k = cur[b][lane];
            { u64 v = cur[b][lane + 64]; if (v < k) k = v; }
            if (lane < NSEG - 128) { u64 v = cur[b][lane + 128]; if (v < k) k = v; }
            k = wave_min_u64(k);
            j1 = (int)(unsigned)(k & 0xffffffffull);
        }
        bool tk = (taken[b][j1 >> 6] >> (j1 & 63)) & 1ull;
        if (!tk) {
            if (lane == 0) { taken[b][j1 >> 6] |= 1ull << (j1 & 63); s_midx[b][i] = j1; }
        } else {
            // collision: first free col is in word 0 (<=32 taken bits ever)
            u64 tw = taken[b][0];
            int bit = __ffsll(~tw) - 1;
            int jf = bit;
            // poison: taken cols below jf (word 0) + contested col j1 (any word)
            u64 add = (lane == 0) ? (tw & ((bit == 0) ? 0ull : ((1ull << bit) - 1ull))) : 0ull;
            if ((j1 >> 6) == lane) add |= 1ull << (j1 & 63);
            if (add) poison[b][lane] |= add;
            int u2 = lane + 64;
            if ((j1 >> 6) == u2) poison[b][u2] |= 1ull << (j1 & 63);
            int u3 = lane + 128;
            if (u3 < NSEG && (j1 >> 6) == u3) poison[b][u3] |= 1ull << (j1 & 63);
            if (lane == 0) { taken[b][0] |= 1ull << bit; s_midx[b][i] = jf; }
        }
    }

    // ---- per-wave finalize partials for batch b (wave-local) ----
    if (lane < 32) {
        int m = lane, j = s_midx[b][m];
        const float* pr = Ob + (size_t)j * ROW;
        float xc = pr[0], yc = pr[1], ww = pr[2], hh = pr[3];
        float x1 = xc - ww * 0.5f, y1 = yc - hh * 0.5f;
        float x2 = xc + ww * 0.5f, y2 = yc + hh * 0.5f;
        float atan_p = atanf((x2 - x1) / (y2 - y1));
        const float* gp = &s_gt[b][m * 5];
        s_siou[b][m] = ciou_f(x1, y1, x2, y2, gp[0], gp[1], gp[2], gp[3], atan_p, gp[4]);
        float conf = pr[4];
        s_adj[b][m] = focal_t(conf, 1.f) - focal_t(conf, 0.f);
    }
    for (int m = 0; m < NGT; ++m) {
        int j = s_midx[b][m];
        const float* pr = Ob + (size_t)j * ROW;
        const float* gt = targets + ((size_t)b * NGT + m) * ROW;
        float s = focal_t(pr[5 + lane], gt[5 + lane]);
        if (lane < 16) s += focal_t(pr[69 + lane], gt[69 + lane]);
        #pragma unroll
        for (int off = 32; off >= 1; off >>= 1) s += __shfl_xor(s, off);
        if (lane == 0) s_cls[b][m] = s / 80.f;
    }
    {
        double ng = buckets[b * NSEG + lane] + buckets[b * NSEG + 64 + lane]
                  + ((lane < 4) ? buckets[b * NSEG + 128 + lane] : 0.0);
        #pragma unroll
        for (int off = 32; off >= 1; off >>= 1) ng += __shfl_xor(ng, off);
        if (lane == 0) s_ns[b] = ng;
    }
    __syncthreads();

    // ---- wave 0: fixed-order combine, write out ----
    if (w == 0) {
        const float* fs = &s_siou[0][0];   // 128 contiguous floats
        const float* fc = &s_cls[0][0];
        const float* fa = &s_adj[0][0];
        double ss = (double)fs[lane] + (double)fs[lane + 64];
        double cs = (double)fc[lane] + (double)fc[lane + 64];
        double as = (double)fa[lane] + (double)fa[lane + 64];
        double ns = (lane < NB) ? s_ns[lane] : 0.0;
        #pragma unroll
        for (int off = 32; off >= 1; off >>= 1) {
            ss += __shfl_xor(ss, off);
            cs += __shfl_xor(cs, off);
            as += __shfl_xor(as, off);
            ns += __shfl_xor(ns, off);
        }
        if (lane == 0) {
            float siou = (float)(ss / 128.0);
            float cls  = (float)(cs / 128.0);
            float obj  = (float)((ns + as) / (double)(NB * NPRED));
            out[0] = 2.0f * siou + 2.0f * obj + 2.0f * cls;
            out[1] = siou;
            out[2] = obj;
            out[3] = cls;
        }
    }
}

// ---------- launch ----------

extern "C" void kernel_launch(void* const* d_in, const int* in_sizes, int n_in,
                              void* d_out, int out_size, void* d_ws, size_t ws_size,
                              hipStream_t stream) {
    const float* outputs = (const float*)d_in[0];
    const float* targets = (const float*)d_in[1];
    float* out = (float*)d_out;

    char* ws = (char*)d_ws;
    double* buckets = (double*)ws;                    // 4*132*8 = 4224 B
    float* gtab = (float*)(ws + 4352);                // 4*32*5*4 = 2560 B
    int* larr = (int*)(ws + 7040);                    // 512 B
    float* s0arr = (float*)(ws + 7552);               // 134400 B
    u64* kt = (u64*)(ws + 141952);                    // 4*32*132*8 = 135168 B

    dim3 g1(NSEG, NB);                                // 132 x 4 segment blocks
    fused_kernel<<<g1, 256, 0, stream>>>(outputs, targets, s0arr, kt, buckets,
                                         gtab, larr);

    assign_finalize_kernel<<<1, 256, 0, stream>>>(outputs, targets, s0arr, kt,
                                                  buckets, gtab, larr, out);
}

// Round 9
// 72.409 us; speedup vs baseline: 1.2318x; 1.2318x over previous
//
#include <hip/hip_runtime.h>
#include <math.h>

#define NB 4
#define NPRED 8400
#define NGT 32
#define NCLS 80
#define ROW 85
#define NSEG 132    // ceil(8400/64); last segment has 16 preds

typedef unsigned long long u64;

// ---------- math helpers (mirror reference fp32 op order) ----------

__device__ __forceinline__ float focal_t(float x, float t) {
    float p = 1.f / (1.f + expf(-x));
    float ce = (fmaxf(x, 0.f) + log1pf(expf(-fabsf(x)))) - x * t; // logaddexp(0,x) - x*t
    float pt = p * t + (1.f - p) * (1.f - t);
    float ompt = 1.f - pt;
    float loss = ce * (ompt * ompt);              // GAMMA=2
    float at = 0.25f * t + 0.75f * (1.f - t);     // ALPHA=0.25
    return at * loss;
}

__device__ __forceinline__ float ciou_f(float x1, float y1, float x2, float y2,
                                        float x1g, float y1g, float x2g, float y2g,
                                        float atan_p, float atan_g) {
    float w1 = x2 - x1, h1 = y2 - y1;
    float wg = x2g - x1g, hg = y2g - y1g;
    float iw = fmaxf(fminf(x2, x2g) - fmaxf(x1, x1g), 0.f);
    float ih = fmaxf(fminf(y2, y2g) - fmaxf(y1, y1g), 0.f);
    float inter = iw * ih;
    float uni = w1 * h1 + wg * hg - inter;
    float iou = inter / (uni + 1e-7f);
    float cw = fmaxf(x2, x2g) - fminf(x1, x1g);
    float ch = fmaxf(y2, y2g) - fminf(y1, y1g);
    float diag = cw * cw + ch * ch + 1e-7f;
    float dx = (x1 + x2 - x1g - x2g) * 0.5f;
    float dy = (y1 + y2 - y1g - y2g) * 0.5f;
    float rho2 = dx * dx + dy * dy;
    float diou = 1.f - iou + rho2 / diag;
    float dd = atan_g - atan_p;
    const float CV = (float)(4.0 / (M_PI * M_PI));
    float v = CV * (dd * dd);
    float alpha = v / (1.f - iou + v + 1e-7f);
    return diou + alpha * v;
}

__device__ __forceinline__ u64 wave_min_u64(u64 k) {
    #pragma unroll
    for (int off = 32; off >= 1; off >>= 1) {
        u64 o = __shfl_xor(k, off);
        k = (o < k) ? o : k;
    }
    return k;
}

// key packs (cost_bits, col). cost >= 0 always -> bit order == value order,
// low word gives the first-index tie-break.
__device__ __forceinline__ u64 pack_key(float v, int idx) {
    return ((u64)__float_as_uint(v) << 32) | (u64)(unsigned)idx;
}

// ---------- K1: fused GT-preproc + staging + S0 + cost + segment minima ----
// Block = (segment sg, batch b). outputs read ONCE, coalesced float4.
// sg==0 blocks persist gtab/larr for K2. buckets direct-write (no atomics).

__global__ __launch_bounds__(256) void fused_kernel(
        const float* __restrict__ outputs, const float* __restrict__ targets,
        float* __restrict__ s0arr, u64* __restrict__ kt,
        double* __restrict__ buckets, float* __restrict__ gtab,
        int* __restrict__ larr) {
    int sg = blockIdx.x, b = blockIdx.y;
    int tid = threadIdx.x;
    int w = tid >> 6, lane = tid & 63;
    int p0 = sg * 64;
    int nv = (sg == NSEG - 1) ? (NPRED - (NSEG - 1) * 64) : 64;   // 16 or 64

    __shared__ float rows[64 * ROW];        // stride 85 floats -> conflict-free
    __shared__ float s_part[4 * 64];
    __shared__ float s_s0[64];
    __shared__ float s_gt[NGT * 5];
    __shared__ int   s_lab[NGT];

    // stage pred rows coalesced (contiguous, 16B-aligned)
    const float4* src4 = (const float4*)(outputs + ((size_t)b * NPRED + p0) * ROW);
    float4* dst4 = (float4*)rows;
    int cnt4 = nv * ROW / 4;                // 1360 or 340, exact
    for (int k = tid; k < cnt4; k += 256) dst4[k] = src4[k];

    // GT boxes (parallel) — same math as reference xywh_to_xyxy + atan
    if (tid < 32) {
        const float* gt = targets + (size_t)(b * NGT + tid) * ROW;
        float xc = gt[0], yc = gt[1], ww = gt[2], hh = gt[3];
        float x1 = xc - ww * 0.5f, y1 = yc - hh * 0.5f;
        float x2 = xc + ww * 0.5f, y2 = yc + hh * 0.5f;
        float at = atanf((x2 - x1) / (y2 - y1));
        s_gt[tid * 5 + 0] = x1; s_gt[tid * 5 + 1] = y1;
        s_gt[tid * 5 + 2] = x2; s_gt[tid * 5 + 3] = y2;
        s_gt[tid * 5 + 4] = at;
        if (sg == 0) {
            float* gp = gtab + (size_t)(b * NGT + tid) * 5;
            gp[0] = x1; gp[1] = y1; gp[2] = x2; gp[3] = y2; gp[4] = at;
        }
    }
    // labels via ballot over the one-hot row (wave w -> 8 GT rows)
    #pragma unroll
    for (int q = 0; q < 8; ++q) {
        int m = w * 8 + q;
        const float* gt = targets + (size_t)(b * NGT + m) * ROW;
        u64 m1 = __ballot(gt[5 + lane] > 0.5f);
        float v2 = (lane < 16) ? gt[69 + lane] : 0.f;
        u64 m2 = __ballot(v2 > 0.5f);
        if (lane == 0) {
            int L = m1 ? (__ffsll(m1) - 1) : (64 + __ffsll(m2) - 1);
            s_lab[m] = L;
            if (sg == 0) larr[b * NGT + m] = L;
        }
    }
    __syncthreads();

    // S0: pred = lane, chunk w covers 20 classes
    {
        float s = 0.f;
        if (lane < nv) {
            const float* r = rows + lane * ROW;
            int c0 = w * 20;
            #pragma unroll
            for (int c = 0; c < 20; ++c) s += focal_t(r[5 + c0 + c], 0.f);
        }
        s_part[w * 64 + lane] = s;
    }
    __syncthreads();
    if (tid < 64) {
        float s = s_part[tid] + s_part[64 + tid] + s_part[128 + tid] + s_part[192 + tid];
        s_s0[tid] = s;
        if (tid < nv) s0arr[b * NPRED + p0 + tid] = s;
        double ng = (tid < nv) ? (double)focal_t(rows[tid * ROW + 4], 0.f) : 0.0;
        #pragma unroll
        for (int off = 32; off >= 1; off >>= 1) ng += __shfl_xor(ng, off);
        if (tid == 0) buckets[b * NSEG + sg] = ng;   // direct write, no atomic
    }
    __syncthreads();

    // cost + packed segment minima: wave w -> GT rows w*8..w*8+7, lane = pred
    bool valid = lane < nv;
    const float* r = rows + lane * ROW;
    float x1 = 0.f, y1 = 0.f, x2 = 0.f, y2 = 0.f, atan_p = 0.f, S0 = 0.f;
    if (valid) {
        float xc = r[0], yc = r[1], ww = r[2], hh = r[3];
        x1 = xc - ww * 0.5f; y1 = yc - hh * 0.5f;
        x2 = xc + ww * 0.5f; y2 = yc + hh * 0.5f;
        atan_p = atanf((x2 - x1) / (y2 - y1));
        S0 = s_s0[lane];
    }
    #pragma unroll
    for (int q = 0; q < 8; ++q) {
        int m = w * 8 + q;
        const float* gp = s_gt + m * 5;
        float cost = INFINITY;
        if (valid) {
            float cc = ciou_f(x1, y1, x2, y2, gp[0], gp[1], gp[2], gp[3],
                              atan_p, gp[4]);
            float xl = r[5 + s_lab[m]];
            cost = cc + (S0 - focal_t(xl, 0.f) + focal_t(xl, 1.f)) / 80.f;
        }
        u64 key = pack_key(cost, valid ? (p0 + lane) : NPRED);
        key = wave_min_u64(key);
        if (lane == 0) kt[(size_t)(b * NGT + m) * NSEG + sg] = key;
    }
}

// ---------- K2: ONE block, 1024 threads (16 waves) -----------------------
// Phase 1: all 16 waves do coalesced rowmin over kt (8 rows each).
// Phase 2: waves 0-3 = serial per-batch assignment (reference semantics,
//          unchanged bitmask logic from R7); waves 4-7 = bucket sums.
// Phase 3: finalize partials spread over all waves; wave-0 combine.
// All state LDS-private to this block; deterministic; no ws-carried state.

__global__ __launch_bounds__(1024) void assign_finalize_kernel(
        const float* __restrict__ outputs, const float* __restrict__ targets,
        const float* __restrict__ s0arr, const u64* __restrict__ kt,
        const double* __restrict__ buckets, const float* __restrict__ gtab,
        const int* __restrict__ larr, float* __restrict__ out) {
    int tid = threadIdx.x;
    int w = tid >> 6, lane = tid & 63;

    __shared__ u64    cur[NB][NSEG];
    __shared__ u64    taken[NB][NSEG], poison[NB][NSEG];
    __shared__ float  s_gt[NB * NGT * 5];     // 640
    __shared__ int    s_lab[NB * NGT];        // 128
    __shared__ int    rmi[NB][NGT];
    __shared__ int    s_midx[NB][NGT];
    __shared__ float  s_siou[NB * NGT], s_cls[NB * NGT], s_adj[NB * NGT];
    __shared__ double s_ns[NB];

    for (int k = tid; k < NB * NSEG; k += 1024) {
        ((u64*)taken)[k] = 0ull; ((u64*)poison)[k] = 0ull;
    }
    if (tid < NB * NGT * 5) s_gt[tid] = gtab[tid];
    if (tid < NB * NGT) s_lab[tid] = larr[tid];

    // Phase 1: rowmin, wave w -> rows w*8..w*8+7 (row = b*32+r), coalesced
    #pragma unroll
    for (int q = 0; q < 8; ++q) {
        int row = w * 8 + q;
        const u64* kr = kt + (size_t)row * NSEG;
        u64 k = kr[lane];
        { u64 v = kr[lane + 64]; if (v < k) k = v; }
        if (lane < NSEG - 128) { u64 v = kr[lane + 128]; if (v < k) k = v; }
        k = wave_min_u64(k);
        if (lane == 0) rmi[row >> 5][row & 31] = (int)(unsigned)(k & 0xffffffffull);
    }
    __syncthreads();

    // Phase 2a: waves 0-3 run the serial assignment for batch b=w
    if (w < NB) {
        int b = w;
        const float* Ob = outputs + (size_t)b * NPRED * ROW;
        const float* S0b = s0arr + (size_t)b * NPRED;
        for (int i = 0; i < NGT; ++i) {
            int j1 = rmi[b][i];
            if ((poison[b][j1 >> 6] >> (j1 & 63)) & 1ull) {
                // lazy repair: copy pristine row keys, recompute poisoned-argmin segs
                const u64* kr = kt + ((size_t)b * NGT + i) * NSEG;
                for (int s = lane; s < NSEG; s += 64) cur[b][s] = kr[s];
                const float* gp = &s_gt[(b * NGT + i) * 5];
                int lab = s_lab[b * NGT + i];
                for (int k0 = 0; k0 < NSEG; k0 += 64) {
                    int s = k0 + lane;
                    int idx0 = (s < NSEG) ? (int)(unsigned)(cur[b][s] & 0xffffffffull) : 0;
                    bool inval = (s < NSEG) && (((poison[b][idx0 >> 6] >> (idx0 & 63)) & 1ull) != 0);
                    u64 im = __ballot(inval);
                    while (im) {
                        int sgg = k0 + (__ffsll(im) - 1);
                        im &= im - 1;
                        int col = (sgg << 6) + lane;
                        bool cv = (col < NPRED) && !((poison[b][col >> 6] >> (col & 63)) & 1ull);
                        float vv = INFINITY;
                        if (cv) {
                            const float* pr = Ob + (size_t)col * ROW;
                            float xc = pr[0], yc = pr[1], ww = pr[2], hh = pr[3];
                            float x1 = xc - ww * 0.5f, y1 = yc - hh * 0.5f;
                            float x2 = xc + ww * 0.5f, y2 = yc + hh * 0.5f;
                            float atan_p = atanf((x2 - x1) / (y2 - y1));
                            float cc = ciou_f(x1, y1, x2, y2, gp[0], gp[1], gp[2], gp[3],
                                              atan_p, gp[4]);
                            float xl = pr[5 + lab];
                            vv = cc + (S0b[col] - focal_t(xl, 0.f) + focal_t(xl, 1.f)) / 80.f;
                        }
                        u64 key = pack_key(vv, cv ? col : NPRED);
                        key = wave_min_u64(key);
                        if (lane == 0) cur[b][sgg] = key;
                    }
                }
                u64 k = cur[b][lane];
                { u64 v = cur[b][lane + 64]; if (v < k) k = v; }
                if (lane < NSEG - 128) { u64 v = cur[b][lane + 128]; if (v < k) k = v; }
                k = wave_min_u64(k);
                j1 = (int)(unsigned)(k & 0xffffffffull);
            }
            bool tk = (taken[b][j1 >> 6] >> (j1 & 63)) & 1ull;
            if (!tk) {
                if (lane == 0) { taken[b][j1 >> 6] |= 1ull << (j1 & 63); s_midx[b][i] = j1; }
            } else {
                // collision: first free col is in word 0 (<=32 taken bits ever)
                u64 tw = taken[b][0];
                int bit = __ffsll(~tw) - 1;
                u64 add = (lane == 0) ? (tw & ((bit == 0) ? 0ull : ((1ull << bit) - 1ull))) : 0ull;
                if ((j1 >> 6) == lane) add |= 1ull << (j1 & 63);
                if (add) poison[b][lane] |= add;
                int u2 = lane + 64;
                if ((j1 >> 6) == u2) poison[b][u2] |= 1ull << (j1 & 63);
                int u3 = lane + 128;
                if (u3 < NSEG && (j1 >> 6) == u3) poison[b][u3] |= 1ull << (j1 & 63);
                if (lane == 0) { taken[b][0] |= 1ull << bit; s_midx[b][i] = bit; }
            }
        }
    } else if (w < 2 * NB) {
        // Phase 2b: waves 4-7 sum neg buckets for batch b=w-4 (concurrent)
        int b = w - NB;
        double ng = buckets[b * NSEG + lane] + buckets[b * NSEG + 64 + lane]
                  + ((lane < NSEG - 128) ? buckets[b * NSEG + 128 + lane] : 0.0);
        #pragma unroll
        for (int off = 32; off >= 1; off >>= 1) ng += __shfl_xor(ng, off);
        if (lane == 0) s_ns[b] = ng;
    }
    __syncthreads();

    // Phase 3: finalize partials
    if (tid < NB * NGT) {          // 128 threads: ciou + obj-adjust per pair
        int b = tid >> 5, m = tid & 31;
        int j = s_midx[b][m];
        const float* pr = outputs + ((size_t)b * NPRED + j) * ROW;
        float xc = pr[0], yc = pr[1], ww = pr[2], hh = pr[3];
        float x1 = xc - ww * 0.5f, y1 = yc - hh * 0.5f;
        float x2 = xc + ww * 0.5f, y2 = yc + hh * 0.5f;
        float atan_p = atanf((x2 - x1) / (y2 - y1));
        const float* gp = &s_gt[tid * 5];
        s_siou[tid] = ciou_f(x1, y1, x2, y2, gp[0], gp[1], gp[2], gp[3], atan_p, gp[4]);
        float conf = pr[4];
        s_adj[tid] = focal_t(conf, 1.f) - focal_t(conf, 0.f);
    }
    // cls: wave w -> pairs w*8..w*8+7, lane-parallel over classes
    #pragma unroll
    for (int q = 0; q < 8; ++q) {
        int p = w * 8 + q;
        int b = p >> 5, m = p & 31;
        int j = s_midx[b][m];
        const float* pr = outputs + ((size_t)b * NPRED + j) * ROW;
        const float* gt = targets + ((size_t)b * NGT + m) * ROW;
        float s = focal_t(pr[5 + lane], gt[5 + lane]);
        if (lane < 16) s += focal_t(pr[69 + lane], gt[69 + lane]);
        #pragma unroll
        for (int off = 32; off >= 1; off >>= 1) s += __shfl_xor(s, off);
        if (lane == 0) s_cls[p] = s / 80.f;
    }
    __syncthreads();

    // wave 0: fixed-order combine, write out
    if (w == 0) {
        double ss = (double)s_siou[lane] + (double)s_siou[lane + 64];
        double cs = (double)s_cls[lane] + (double)s_cls[lane + 64];
        double as = (double)s_adj[lane] + (double)s_adj[lane + 64];
        double ns = (lane < NB) ? s_ns[lane] : 0.0;
        #pragma unroll
        for (int off = 32; off >= 1; off >>= 1) {
            ss += __shfl_xor(ss, off);
            cs += __shfl_xor(cs, off);
            as += __shfl_xor(as, off);
            ns += __shfl_xor(ns, off);
        }
        if (lane == 0) {
            float siou = (float)(ss / 128.0);
            float cls  = (float)(cs / 128.0);
            float obj  = (float)((ns + as) / (double)(NB * NPRED));
            out[0] = 2.0f * siou + 2.0f * obj + 2.0f * cls;
            out[1] = siou;
            out[2] = obj;
            out[3] = cls;
        }
    }
}

// ---------- launch ----------

extern "C" void kernel_launch(void* const* d_in, const int* in_sizes, int n_in,
                              void* d_out, int out_size, void* d_ws, size_t ws_size,
                              hipStream_t stream) {
    const float* outputs = (const float*)d_in[0];
    const float* targets = (const float*)d_in[1];
    float* out = (float*)d_out;

    char* ws = (char*)d_ws;
    double* buckets = (double*)ws;                    // 4*132*8 = 4224 B
    float* gtab = (float*)(ws + 4352);                // 4*32*5*4 = 2560 B
    int* larr = (int*)(ws + 7040);                    // 512 B
    float* s0arr = (float*)(ws + 7552);               // 134400 B
    u64* kt = (u64*)(ws + 141952);                    // 4*32*132*8 = 135168 B

    dim3 g1(NSEG, NB);                                // 132 x 4 segment blocks
    fused_kernel<<<g1, 256, 0, stream>>>(outputs, targets, s0arr, kt, buckets,
                                         gtab, larr);

    assign_finalize_kernel<<<1, 1024, 0, stream>>>(outputs, targets, s0arr, kt,
                                                   buckets, gtab, larr, out);
}